// Round 1
// baseline (375.554 us; speedup 1.0000x reference)
//
#include <hip/hip_runtime.h>
#include <hip/hip_bf16.h>
#include <cstdint>
#include <cstddef>

#define BB 2
#define NN 2048
#define CC 768
#define HH 12
#define DD 64
#define HID 3072
#define TT (BB*NN)   // 4096 tokens

typedef __attribute__((ext_vector_type(8))) short bf16x8;
typedef __attribute__((ext_vector_type(4))) short bf16x4;
typedef __attribute__((ext_vector_type(4))) float f32x4;

__device__ __forceinline__ unsigned short f2bf(float f) {
    unsigned int u = __float_as_uint(f);
    u += 0x7fffu + ((u >> 16) & 1u);
    return (unsigned short)(u >> 16);
}

// ---------------- fp32 -> bf16 convert ----------------
__global__ __launch_bounds__(256) void cvt_kernel(const float* __restrict__ in,
                                                  unsigned short* __restrict__ out, int n) {
    int i = blockIdx.x * 256 + threadIdx.x;
    int stride = gridDim.x * 256;
    for (; i < n; i += stride) out[i] = f2bf(in[i]);
}

// ---------------- mask -> bit pack (16 keys per ushort) ----------------
__global__ __launch_bounds__(256) void maskbits_kernel(const float* __restrict__ mask,
                                                       unsigned short* __restrict__ mb, int n) {
    int i = blockIdx.x * 256 + threadIdx.x;
    if (i >= n) return;
    const float* mp = mask + (size_t)i * 16;
    unsigned int bits = 0;
#pragma unroll
    for (int j = 0; j < 16; ++j) bits |= (mp[j] > 0.5f) ? (1u << j) : 0u;
    mb[i] = (unsigned short)bits;
}

// ---------------- LayerNorm (fp32 in, bf16 out) ----------------
__global__ __launch_bounds__(256) void ln_kernel(const float* __restrict__ x,
                                                 const float* __restrict__ g,
                                                 const float* __restrict__ b,
                                                 unsigned short* __restrict__ out) {
    int t = blockIdx.x;
    int tid = threadIdx.x;
    const float* xr = x + (size_t)t * CC;
    float v0 = xr[tid], v1 = xr[tid + 256], v2 = xr[tid + 512];
    float s = v0 + v1 + v2;
    float s2 = v0 * v0 + v1 * v1 + v2 * v2;
#pragma unroll
    for (int off = 1; off < 64; off <<= 1) {
        s  += __shfl_xor(s, off);
        s2 += __shfl_xor(s2, off);
    }
    __shared__ float red[8];
    int wv = tid >> 6, lane = tid & 63;
    if (lane == 0) { red[wv] = s; red[wv + 4] = s2; }
    __syncthreads();
    s  = red[0] + red[1] + red[2] + red[3];
    s2 = red[4] + red[5] + red[6] + red[7];
    float mu   = s * (1.0f / CC);
    float var  = s2 * (1.0f / CC) - mu * mu;
    float rstd = rsqrtf(var + 1e-5f);
    unsigned short* orow = out + (size_t)t * CC;
    orow[tid]       = f2bf((v0 - mu) * rstd * g[tid]       + b[tid]);
    orow[tid + 256] = f2bf((v1 - mu) * rstd * g[tid + 256] + b[tid + 256]);
    orow[tid + 512] = f2bf((v2 - mu) * rstd * g[tid + 512] + b[tid + 512]);
}

// ---------------- GEMM: C[M,N] = A[M,K] @ Bw[N,K]^T (+epilogue) ----------------
// EPI 0: store bf16 (no bias)            -> qkv
// EPI 1: +bias +res(f32), store f32      -> proj + residual
// EPI 2: +bias, exact GELU, store bf16   -> fc1
// EPI 3: +bias +res(f32), store f32      -> fc2 + residual (d_out)
template <int EPI>
__global__ __launch_bounds__(256) void gemm_bt(const unsigned short* __restrict__ A,
                                               const unsigned short* __restrict__ Bw,
                                               const float* __restrict__ bias,
                                               const float* __restrict__ res,
                                               void* __restrict__ out,
                                               int M, int N, int K) {
    __shared__ unsigned short As[128 * 40];
    __shared__ unsigned short Bs[128 * 40];
    int tid = threadIdx.x;
    int lane = tid & 63, wv = tid >> 6;
    int l16 = lane & 15, lg = lane >> 4;
    int bm = blockIdx.x, bn = blockIdx.y;
    int wm = (wv & 1) * 64, wn = (wv >> 1) * 64;

    f32x4 acc[4][4];
#pragma unroll
    for (int i = 0; i < 4; ++i)
#pragma unroll
        for (int j = 0; j < 4; ++j) acc[i][j] = f32x4{0.f, 0.f, 0.f, 0.f};

    const unsigned short* Ab = A + (size_t)bm * 128 * K;
    const unsigned short* Bb = Bw + (size_t)bn * 128 * K;

    for (int k0 = 0; k0 < K; k0 += 32) {
        __syncthreads();
#pragma unroll
        for (int i = 0; i < 2; ++i) {
            int c = tid + i * 256;          // 0..511
            int row = c >> 2, col = (c & 3) * 8;
            *(bf16x8*)&As[row * 40 + col] = *(const bf16x8*)(Ab + (size_t)row * K + k0 + col);
            *(bf16x8*)&Bs[row * 40 + col] = *(const bf16x8*)(Bb + (size_t)row * K + k0 + col);
        }
        __syncthreads();
        bf16x8 af[4], bf[4];
#pragma unroll
        for (int mi = 0; mi < 4; ++mi) af[mi] = *(const bf16x8*)&As[(wm + mi * 16 + l16) * 40 + lg * 8];
#pragma unroll
        for (int ni = 0; ni < 4; ++ni) bf[ni] = *(const bf16x8*)&Bs[(wn + ni * 16 + l16) * 40 + lg * 8];
#pragma unroll
        for (int mi = 0; mi < 4; ++mi)
#pragma unroll
            for (int ni = 0; ni < 4; ++ni)
                acc[mi][ni] = __builtin_amdgcn_mfma_f32_16x16x32_bf16(af[mi], bf[ni], acc[mi][ni], 0, 0, 0);
    }

#pragma unroll
    for (int mi = 0; mi < 4; ++mi)
#pragma unroll
        for (int ni = 0; ni < 4; ++ni) {
            int col = bn * 128 + wn + ni * 16 + l16;
            float bv = (EPI == 0) ? 0.f : bias[col];
#pragma unroll
            for (int r = 0; r < 4; ++r) {
                int row = bm * 128 + wm + mi * 16 + lg * 4 + r;
                float v = acc[mi][ni][r];
                size_t idx = (size_t)row * N + col;
                if (EPI == 0) {
                    ((unsigned short*)out)[idx] = f2bf(v);
                } else if (EPI == 1) {
                    ((float*)out)[idx] = v + bv + res[idx];
                } else if (EPI == 2) {
                    v += bv;
                    v = 0.5f * v * (1.0f + erff(v * 0.70710678118f));
                    ((unsigned short*)out)[idx] = f2bf(v);
                } else {
                    ((float*)out)[idx] = v + bv + res[idx];
                }
            }
        }
}

// ---------------- Flash attention ----------------
// qkv: [T, 2304] bf16 (q | k | v per token), maskb: [B*N, 128] ushort bitmask
// o:   [T, 768] bf16 (b, n, h, d)
__global__ __launch_bounds__(256) void attn_kernel(const unsigned short* __restrict__ qkv,
                                                   const unsigned short* __restrict__ maskb,
                                                   unsigned short* __restrict__ o) {
    int tid = threadIdx.x;
    int lane = tid & 63, wv = tid >> 6;
    int l16 = lane & 15, lg = lane >> 4;
    int qb = blockIdx.x;            // 0..31 (blocks of 64 q rows)
    int bh = blockIdx.y;            // 0..23
    int b = bh / HH, h = bh % HH;
    int qrow = qb * 64 + wv * 16 + l16;   // 0..2047

    const unsigned short* qp = qkv + ((size_t)(b * NN + qrow)) * 2304 + h * DD;
    bf16x8 q0 = *(const bf16x8*)(qp + 8 * lg);
    bf16x8 q1 = *(const bf16x8*)(qp + 32 + 8 * lg);
    const unsigned short* mrow = maskb + ((size_t)(b * NN + qrow)) * 128;
    const unsigned short* kbase = qkv + (size_t)b * NN * 2304 + 768 + h * DD;
    const unsigned short* vbase = qkv + (size_t)b * NN * 2304 + 1536 + h * DD;

    f32x4 oa[4];
#pragma unroll
    for (int i = 0; i < 4; ++i) oa[i] = f32x4{0.f, 0.f, 0.f, 0.f};
    float mrun = -INFINITY, lrun = 0.f;

    for (int kt = 0; kt < NN / 16; ++kt) {
        const unsigned short* kp = kbase + (size_t)(kt * 16 + l16) * 2304;
        bf16x8 k0 = *(const bf16x8*)(kp + 8 * lg);
        bf16x8 k1 = *(const bf16x8*)(kp + 32 + 8 * lg);
        f32x4 sa = f32x4{0.f, 0.f, 0.f, 0.f};
        // S^T[key][qrow], key = lg*4 + r, qrow = l16
        sa = __builtin_amdgcn_mfma_f32_16x16x32_bf16(k0, q0, sa, 0, 0, 0);
        sa = __builtin_amdgcn_mfma_f32_16x16x32_bf16(k1, q1, sa, 0, 0, 0);
        unsigned int bits = mrow[kt];
        float sv[4];
        float tmax = -INFINITY;
#pragma unroll
        for (int r = 0; r < 4; ++r) {
            float xs = sa[r] * 0.125f;
            if ((bits >> (lg * 4 + r)) & 1) xs -= 100000.0f;
            sv[r] = xs;
            tmax = fmaxf(tmax, xs);
        }
        tmax = fmaxf(tmax, __shfl_xor(tmax, 16));
        tmax = fmaxf(tmax, __shfl_xor(tmax, 32));
        float mnew = fmaxf(mrun, tmax);
        float sc = __expf(mrun - mnew);
        float p[4], ps = 0.f;
#pragma unroll
        for (int r = 0; r < 4; ++r) { p[r] = __expf(sv[r] - mnew); ps += p[r]; }
        lrun = lrun * sc + ps;
        mrun = mnew;
        bf16x4 pf;
#pragma unroll
        for (int r = 0; r < 4; ++r) pf[r] = (short)f2bf(p[r]);
#pragma unroll
        for (int db = 0; db < 4; ++db) {
            oa[db][0] *= sc; oa[db][1] *= sc; oa[db][2] *= sc; oa[db][3] *= sc;
            const unsigned short* vp = vbase + db * 16 + l16;
            bf16x4 vf;
#pragma unroll
            for (int j = 0; j < 4; ++j) vf[j] = (short)vp[(size_t)(kt * 16 + lg * 4 + j) * 2304];
            oa[db] = __builtin_amdgcn_mfma_f32_16x16x16bf16_1k(vf, pf, oa[db], 0, 0, 0);
        }
    }
    float lt = lrun;
    lt += __shfl_xor(lt, 16);
    lt += __shfl_xor(lt, 32);
    float inv = 1.0f / lt;
    unsigned short* op = o + ((size_t)(b * NN + qrow)) * CC + h * DD;
#pragma unroll
    for (int db = 0; db < 4; ++db)
#pragma unroll
        for (int r = 0; r < 4; ++r)
            op[db * 16 + lg * 4 + r] = f2bf(oa[db][r] * inv);
}

// ---------------- host launch ----------------
extern "C" void kernel_launch(void* const* d_in, const int* in_sizes, int n_in,
                              void* d_out, int out_size, void* d_ws, size_t ws_size,
                              hipStream_t stream) {
    const float* x    = (const float*)d_in[0];
    const float* mask = (const float*)d_in[1];
    const float* g1   = (const float*)d_in[2];
    const float* b1   = (const float*)d_in[3];
    const float* Wq   = (const float*)d_in[4];
    const float* Wkv  = (const float*)d_in[5];
    const float* Wp   = (const float*)d_in[6];
    const float* bp   = (const float*)d_in[7];
    const float* g2   = (const float*)d_in[8];
    const float* b2   = (const float*)d_in[9];
    const float* W1   = (const float*)d_in[10];
    const float* bf1  = (const float*)d_in[11];
    const float* W2   = (const float*)d_in[12];
    const float* bf2  = (const float*)d_in[13];
    float* out = (float*)d_out;

    char* w = (char*)d_ws;
    unsigned short* wqkv = (unsigned short*)w;      w += (size_t)2304 * 768 * 2;   // 3.5 MB
    unsigned short* wp   = (unsigned short*)w;      w += (size_t)768 * 768 * 2;
    unsigned short* w1   = (unsigned short*)w;      w += (size_t)3072 * 768 * 2;
    unsigned short* w2   = (unsigned short*)w;      w += (size_t)768 * 3072 * 2;
    unsigned short* xn   = (unsigned short*)w;      w += (size_t)TT * CC * 2;
    unsigned short* qkv  = (unsigned short*)w;      w += (size_t)TT * 2304 * 2;
    unsigned short* mb   = (unsigned short*)w;      w += (size_t)BB * NN * 128 * 2;
    unsigned short* obuf = (unsigned short*)w;      w += (size_t)TT * CC * 2;
    float*          x1   = (float*)w;               w += (size_t)TT * CC * 4;
    unsigned short* xn2  = (unsigned short*)w;      w += (size_t)TT * CC * 2;
    unsigned short* hbuf = (unsigned short*)w;      w += (size_t)TT * HID * 2;

    // weight conversions
    cvt_kernel<<<1024, 256, 0, stream>>>(Wq,  wqkv,                 768 * 768);
    cvt_kernel<<<1024, 256, 0, stream>>>(Wkv, wqkv + 768 * 768,     1536 * 768);
    cvt_kernel<<<1024, 256, 0, stream>>>(Wp,  wp,                   768 * 768);
    cvt_kernel<<<2048, 256, 0, stream>>>(W1,  w1,                   3072 * 768);
    cvt_kernel<<<2048, 256, 0, stream>>>(W2,  w2,                   768 * 3072);

    // mask bits: B*N*(N/16) ushorts
    {
        int n = BB * NN * (NN / 16);
        maskbits_kernel<<<(n + 255) / 256, 256, 0, stream>>>(mask, mb, n);
    }

    // LN1
    ln_kernel<<<TT, 256, 0, stream>>>(x, g1, b1, xn);

    // QKV gemm: [4096,768] @ [2304,768]^T -> bf16 [4096,2304]
    gemm_bt<0><<<dim3(TT / 128, 2304 / 128), 256, 0, stream>>>(xn, wqkv, nullptr, nullptr, qkv, TT, 2304, 768);

    // attention
    attn_kernel<<<dim3(NN / 64, BB * HH), 256, 0, stream>>>(qkv, mb, obuf);

    // proj + residual -> x1 (f32)
    gemm_bt<1><<<dim3(TT / 128, 768 / 128), 256, 0, stream>>>(obuf, wp, bp, x, x1, TT, 768, 768);

    // LN2
    ln_kernel<<<TT, 256, 0, stream>>>(x1, g2, b2, xn2);

    // fc1 + gelu -> h (bf16)
    gemm_bt<2><<<dim3(TT / 128, HID / 128), 256, 0, stream>>>(xn2, w1, bf1, nullptr, hbuf, TT, HID, 768);

    // fc2 + bias + residual -> out (f32)
    gemm_bt<3><<<dim3(TT / 128, 768 / 128), 256, 0, stream>>>(hbuf, w2, bf2, x1, out, TT, 768, HID);
}

// Round 2
// 269.461 us; speedup vs baseline: 1.3937x; 1.3937x over previous
//
#include <hip/hip_runtime.h>
#include <hip/hip_bf16.h>
#include <cstdint>
#include <cstddef>

#define BB 2
#define NN 2048
#define CC 768
#define HH 12
#define DD 64
#define HID 3072
#define TT (BB*NN)   // 4096 tokens

typedef __attribute__((ext_vector_type(8))) short bf16x8;
typedef __attribute__((ext_vector_type(4))) short bf16x4;
typedef __attribute__((ext_vector_type(4))) float f32x4;

__device__ __forceinline__ unsigned short f2bf(float f) {
    unsigned int u = __float_as_uint(f);
    u += 0x7fffu + ((u >> 16) & 1u);
    return (unsigned short)(u >> 16);
}

// async global -> LDS, 16 bytes per lane (dest must be base + lane*16)
__device__ __forceinline__ void gload16(const void* g, void* l) {
    __builtin_amdgcn_global_load_lds((__attribute__((address_space(1))) unsigned int*)g,
                                     (__attribute__((address_space(3))) unsigned int*)l,
                                     16, 0, 0);
}

// ---------------- fp32 -> bf16 convert ----------------
__global__ __launch_bounds__(256) void cvt_kernel(const float* __restrict__ in,
                                                  unsigned short* __restrict__ out, int n) {
    int i = blockIdx.x * 256 + threadIdx.x;
    int stride = gridDim.x * 256;
    for (; i < n; i += stride) out[i] = f2bf(in[i]);
}

// ---------------- mask -> bit pack (16 keys per ushort) ----------------
__global__ __launch_bounds__(256) void maskbits_kernel(const float* __restrict__ mask,
                                                       unsigned short* __restrict__ mb, int n) {
    int i = blockIdx.x * 256 + threadIdx.x;
    if (i >= n) return;
    const float* mp = mask + (size_t)i * 16;
    unsigned int bits = 0;
#pragma unroll
    for (int j = 0; j < 16; ++j) bits |= (mp[j] > 0.5f) ? (1u << j) : 0u;
    mb[i] = (unsigned short)bits;
}

// ---------------- LayerNorm (fp32 in, bf16 out) ----------------
__global__ __launch_bounds__(256) void ln_kernel(const float* __restrict__ x,
                                                 const float* __restrict__ g,
                                                 const float* __restrict__ b,
                                                 unsigned short* __restrict__ out) {
    int t = blockIdx.x;
    int tid = threadIdx.x;
    const float* xr = x + (size_t)t * CC;
    float v0 = xr[tid], v1 = xr[tid + 256], v2 = xr[tid + 512];
    float s = v0 + v1 + v2;
    float s2 = v0 * v0 + v1 * v1 + v2 * v2;
#pragma unroll
    for (int off = 1; off < 64; off <<= 1) {
        s  += __shfl_xor(s, off);
        s2 += __shfl_xor(s2, off);
    }
    __shared__ float red[8];
    int wv = tid >> 6, lane = tid & 63;
    if (lane == 0) { red[wv] = s; red[wv + 4] = s2; }
    __syncthreads();
    s  = red[0] + red[1] + red[2] + red[3];
    s2 = red[4] + red[5] + red[6] + red[7];
    float mu   = s * (1.0f / CC);
    float var  = s2 * (1.0f / CC) - mu * mu;
    float rstd = rsqrtf(var + 1e-5f);
    unsigned short* orow = out + (size_t)t * CC;
    orow[tid]       = f2bf((v0 - mu) * rstd * g[tid]       + b[tid]);
    orow[tid + 256] = f2bf((v1 - mu) * rstd * g[tid + 256] + b[tid + 256]);
    orow[tid + 512] = f2bf((v2 - mu) * rstd * g[tid + 512] + b[tid + 512]);
}

// ---------------- GEMM (m97 structure): C[M,N] = A[M,K] @ Bw[N,K]^T ----------------
// EPI 0: store bf16 (no bias)            -> qkv
// EPI 1: +bias +res(f32), store f32      -> proj + residual
// EPI 2: +bias, exact GELU, store bf16   -> fc1
// EPI 3: +bias +res(f32), store f32      -> fc2 + residual (d_out)
template <int EPI>
__global__ __launch_bounds__(256) void gemm_bt(const unsigned short* __restrict__ A,
                                               const unsigned short* __restrict__ Bw,
                                               const float* __restrict__ bias,
                                               const float* __restrict__ res,
                                               void* __restrict__ out,
                                               int M, int N, int K) {
    __shared__ alignas(16) unsigned short As[128 * 32];
    __shared__ alignas(16) unsigned short Bs[128 * 32];
    int tid = threadIdx.x;
    int lane = tid & 63, wv = tid >> 6;
    int l16 = lane & 15, lg = lane >> 4;
    int bm = blockIdx.x, bn = blockIdx.y;
    int wm = (wv & 1) * 64, wn = (wv >> 1) * 64;

    f32x4 acc[4][4];
#pragma unroll
    for (int i = 0; i < 4; ++i)
#pragma unroll
        for (int j = 0; j < 4; ++j) acc[i][j] = f32x4{0.f, 0.f, 0.f, 0.f};

    const unsigned short* Ab = A + (size_t)bm * 128 * K;
    const unsigned short* Bb = Bw + (size_t)bn * 128 * K;

    for (int k0 = 0; k0 < K; k0 += 32) {
        __syncthreads();
        // stage 128x32 bf16 tiles of A and B, 16B per lane, LDS linear
#pragma unroll
        for (int i = 0; i < 2; ++i) {
            int c = tid + i * 256;           // chunk 0..511, 16B each
            int row = c >> 2, cc = (c & 3) * 8;
            gload16(Ab + (size_t)row * K + k0 + cc, &As[c * 8]);
            gload16(Bb + (size_t)row * K + k0 + cc, &Bs[c * 8]);
        }
        __syncthreads();   // compiler emits s_waitcnt vmcnt(0) before barrier
        bf16x8 af[4], bfr[4];
#pragma unroll
        for (int mi = 0; mi < 4; ++mi) af[mi]  = *(const bf16x8*)&As[(wm + mi * 16 + l16) * 32 + lg * 8];
#pragma unroll
        for (int ni = 0; ni < 4; ++ni) bfr[ni] = *(const bf16x8*)&Bs[(wn + ni * 16 + l16) * 32 + lg * 8];
#pragma unroll
        for (int mi = 0; mi < 4; ++mi)
#pragma unroll
            for (int ni = 0; ni < 4; ++ni)
                acc[mi][ni] = __builtin_amdgcn_mfma_f32_16x16x32_bf16(af[mi], bfr[ni], acc[mi][ni], 0, 0, 0);
    }

#pragma unroll
    for (int mi = 0; mi < 4; ++mi)
#pragma unroll
        for (int ni = 0; ni < 4; ++ni) {
            int col = bn * 128 + wn + ni * 16 + l16;
            float bv = (EPI == 0) ? 0.f : bias[col];
#pragma unroll
            for (int r = 0; r < 4; ++r) {
                int row = bm * 128 + wm + mi * 16 + lg * 4 + r;
                float v = acc[mi][ni][r];
                size_t idx = (size_t)row * N + col;
                if (EPI == 0) {
                    ((unsigned short*)out)[idx] = f2bf(v);
                } else if (EPI == 1) {
                    ((float*)out)[idx] = v + bv + res[idx];
                } else if (EPI == 2) {
                    v += bv;
                    v = 0.5f * v * (1.0f + erff(v * 0.70710678118f));
                    ((unsigned short*)out)[idx] = f2bf(v);
                } else {
                    ((float*)out)[idx] = v + bv + res[idx];
                }
            }
        }
}

// ---------------- Flash attention v2: KVB=64, LDS-staged K (swizzled) + V^T ----------------
// qkv: [T, 2304] bf16 (q | k | v per token), maskb: [B*N, 128] ushort bitmask
// o:   [T, 768] bf16
#define KVB 64
#define VTP 66   // Vt pitch (ushorts)
__global__ __launch_bounds__(256) void attn_kernel(const unsigned short* __restrict__ qkv,
                                                   const unsigned short* __restrict__ maskb,
                                                   unsigned short* __restrict__ o) {
    __shared__ alignas(16) unsigned short Ks[64 * 64];   // [key][d], 16B chunks XOR-swizzled by key&7
    __shared__ alignas(16) unsigned short Vt[64 * VTP];  // [d][key], pitch 66
    int tid = threadIdx.x;
    int lane = tid & 63, wv = tid >> 6;
    int l16 = lane & 15, lg = lane >> 4;
    int qb = blockIdx.x;            // 0..31 (blocks of 64 q rows)
    int bh = blockIdx.y;            // 0..23
    int b = bh / HH, h = bh % HH;
    int qrow = qb * 64 + wv * 16 + l16;

    const unsigned short* qp = qkv + ((size_t)(b * NN + qrow)) * 2304 + h * DD;
    bf16x8 q0 = *(const bf16x8*)(qp + 8 * lg);
    bf16x8 q1 = *(const bf16x8*)(qp + 32 + 8 * lg);
    const unsigned short* mrow  = maskb + ((size_t)(b * NN + qrow)) * 128;
    const unsigned short* kbase = qkv + (size_t)b * NN * 2304 + 768 + h * DD;
    const unsigned short* vbase = qkv + (size_t)b * NN * 2304 + 1536 + h * DD;

    // staging maps
    int v_key = tid >> 2, v_d0 = (tid & 3) * 16;   // V: 4 threads per key row

    f32x4 oa[4];
#pragma unroll
    for (int i = 0; i < 4; ++i) oa[i] = f32x4{0.f, 0.f, 0.f, 0.f};
    float mrun = -INFINITY, lrun = 0.f;

    for (int kt = 0; kt < NN / KVB; ++kt) {
        __syncthreads();
        // ---- stage K tile [64][64], 16B chunks, chunk index XOR key&7 ----
#pragma unroll
        for (int i = 0; i < 2; ++i) {
            int c = tid + i * 256;            // 0..511
            int row = c >> 3, c7 = c & 7;
            bf16x8 kv8 = *(const bf16x8*)(kbase + (size_t)(kt * KVB + row) * 2304 + c7 * 8);
            *(bf16x8*)&Ks[row * 64 + ((c7 ^ (row & 7)) * 8)] = kv8;
        }
        // ---- stage V transposed: Vt[d][key] ----
        {
            const unsigned short* vp = vbase + (size_t)(kt * KVB + v_key) * 2304 + v_d0;
            bf16x8 a0 = *(const bf16x8*)(vp);
            bf16x8 a1 = *(const bf16x8*)(vp + 8);
#pragma unroll
            for (int j = 0; j < 8; ++j) Vt[(v_d0 + j) * VTP + v_key]     = (unsigned short)a0[j];
#pragma unroll
            for (int j = 0; j < 8; ++j) Vt[(v_d0 + 8 + j) * VTP + v_key] = (unsigned short)a1[j];
        }
        __syncthreads();

        unsigned long long mbits = *(const unsigned long long*)(mrow + kt * 4);
        float sv[16];
        float tmax = -INFINITY;
#pragma unroll
        for (int ks = 0; ks < 4; ++ks) {
            int krow = ks * 16 + l16;
            bf16x8 k0 = *(const bf16x8*)&Ks[krow * 64 + ((lg     ^ (krow & 7)) * 8)];
            bf16x8 k1 = *(const bf16x8*)&Ks[krow * 64 + (((lg+4) ^ (krow & 7)) * 8)];
            f32x4 sa = f32x4{0.f, 0.f, 0.f, 0.f};
            sa = __builtin_amdgcn_mfma_f32_16x16x32_bf16(k0, q0, sa, 0, 0, 0);
            sa = __builtin_amdgcn_mfma_f32_16x16x32_bf16(k1, q1, sa, 0, 0, 0);
#pragma unroll
            for (int r = 0; r < 4; ++r) {
                float xs = sa[r] * 0.125f;
                if ((mbits >> (ks * 16 + lg * 4 + r)) & 1) xs -= 100000.0f;
                sv[ks * 4 + r] = xs;
                tmax = fmaxf(tmax, xs);
            }
        }
        tmax = fmaxf(tmax, __shfl_xor(tmax, 16));
        tmax = fmaxf(tmax, __shfl_xor(tmax, 32));
        float mnew = fmaxf(mrun, tmax);
        float sc = __expf(mrun - mnew);
        mrun = mnew;
        float ps = 0.f;
        bf16x4 pf[4];
#pragma unroll
        for (int ks = 0; ks < 4; ++ks)
#pragma unroll
            for (int r = 0; r < 4; ++r) {
                float p = __expf(sv[ks * 4 + r] - mnew);
                ps += p;
                pf[ks][r] = (short)f2bf(p);
            }
        lrun = lrun * sc + ps;
#pragma unroll
        for (int db = 0; db < 4; ++db) {
            oa[db][0] *= sc; oa[db][1] *= sc; oa[db][2] *= sc; oa[db][3] *= sc;
        }
#pragma unroll
        for (int ks = 0; ks < 4; ++ks)
#pragma unroll
            for (int db = 0; db < 4; ++db) {
                bf16x4 vf = *(const bf16x4*)&Vt[(db * 16 + l16) * VTP + ks * 16 + lg * 4];
                oa[db] = __builtin_amdgcn_mfma_f32_16x16x16bf16_1k(vf, pf[ks], oa[db], 0, 0, 0);
            }
    }
    float lt = lrun;
    lt += __shfl_xor(lt, 16);
    lt += __shfl_xor(lt, 32);
    float inv = 1.0f / lt;
    unsigned short* op = o + ((size_t)(b * NN + qrow)) * CC + h * DD;
#pragma unroll
    for (int db = 0; db < 4; ++db) {
        bf16x4 ov;
#pragma unroll
        for (int r = 0; r < 4; ++r) ov[r] = (short)f2bf(oa[db][r] * inv);
        *(bf16x4*)&op[db * 16 + lg * 4] = ov;
    }
}

// ---------------- host launch ----------------
extern "C" void kernel_launch(void* const* d_in, const int* in_sizes, int n_in,
                              void* d_out, int out_size, void* d_ws, size_t ws_size,
                              hipStream_t stream) {
    const float* x    = (const float*)d_in[0];
    const float* mask = (const float*)d_in[1];
    const float* g1   = (const float*)d_in[2];
    const float* b1   = (const float*)d_in[3];
    const float* Wq   = (const float*)d_in[4];
    const float* Wkv  = (const float*)d_in[5];
    const float* Wp   = (const float*)d_in[6];
    const float* bp   = (const float*)d_in[7];
    const float* g2   = (const float*)d_in[8];
    const float* b2   = (const float*)d_in[9];
    const float* W1   = (const float*)d_in[10];
    const float* bf1  = (const float*)d_in[11];
    const float* W2   = (const float*)d_in[12];
    const float* bf2  = (const float*)d_in[13];
    float* out = (float*)d_out;

    char* w = (char*)d_ws;
    unsigned short* wqkv = (unsigned short*)w;      w += (size_t)2304 * 768 * 2;
    unsigned short* wp   = (unsigned short*)w;      w += (size_t)768 * 768 * 2;
    unsigned short* w1   = (unsigned short*)w;      w += (size_t)3072 * 768 * 2;
    unsigned short* w2   = (unsigned short*)w;      w += (size_t)768 * 3072 * 2;
    unsigned short* xn   = (unsigned short*)w;      w += (size_t)TT * CC * 2;
    unsigned short* qkv  = (unsigned short*)w;      w += (size_t)TT * 2304 * 2;
    unsigned short* mb   = (unsigned short*)w;      w += (size_t)BB * NN * 128 * 2;
    unsigned short* obuf = (unsigned short*)w;      w += (size_t)TT * CC * 2;
    float*          x1   = (float*)w;               w += (size_t)TT * CC * 4;
    unsigned short* xn2  = (unsigned short*)w;      w += (size_t)TT * CC * 2;
    unsigned short* hbuf = (unsigned short*)w;      w += (size_t)TT * HID * 2;

    cvt_kernel<<<1024, 256, 0, stream>>>(Wq,  wqkv,             768 * 768);
    cvt_kernel<<<1024, 256, 0, stream>>>(Wkv, wqkv + 768 * 768, 1536 * 768);
    cvt_kernel<<<1024, 256, 0, stream>>>(Wp,  wp,               768 * 768);
    cvt_kernel<<<2048, 256, 0, stream>>>(W1,  w1,               3072 * 768);
    cvt_kernel<<<2048, 256, 0, stream>>>(W2,  w2,               768 * 3072);

    {
        int n = BB * NN * (NN / 16);
        maskbits_kernel<<<(n + 255) / 256, 256, 0, stream>>>(mask, mb, n);
    }

    ln_kernel<<<TT, 256, 0, stream>>>(x, g1, b1, xn);

    gemm_bt<0><<<dim3(TT / 128, 2304 / 128), 256, 0, stream>>>(xn, wqkv, nullptr, nullptr, qkv, TT, 2304, 768);

    attn_kernel<<<dim3(NN / 64, BB * HH), 256, 0, stream>>>(qkv, mb, obuf);

    gemm_bt<1><<<dim3(TT / 128, 768 / 128), 256, 0, stream>>>(obuf, wp, bp, x, x1, TT, 768, 768);

    ln_kernel<<<TT, 256, 0, stream>>>(x1, g2, b2, xn2);

    gemm_bt<2><<<dim3(TT / 128, HID / 128), 256, 0, stream>>>(xn2, w1, bf1, nullptr, hbuf, TT, HID, 768);

    gemm_bt<3><<<dim3(TT / 128, 768 / 128), 256, 0, stream>>>(hbuf, w2, bf2, x1, out, TT, 768, HID);
}

// Round 3
// 226.803 us; speedup vs baseline: 1.6559x; 1.1881x over previous
//
#include <hip/hip_runtime.h>
#include <hip/hip_bf16.h>
#include <cstdint>
#include <cstddef>

#define BB 2
#define NN 2048
#define CC 768
#define HH 12
#define DD 64
#define HID 3072
#define TT (BB*NN)   // 4096 tokens

typedef __attribute__((ext_vector_type(8))) short bf16x8;
typedef __attribute__((ext_vector_type(4))) short bf16x4;
typedef __attribute__((ext_vector_type(4))) float f32x4;

__device__ __forceinline__ unsigned short f2bf(float f) {
    unsigned int u = __float_as_uint(f);
    u += 0x7fffu + ((u >> 16) & 1u);
    return (unsigned short)(u >> 16);
}
__device__ __forceinline__ float bf2f(unsigned short u) {
    return __uint_as_float(((unsigned int)u) << 16);
}
#if __has_builtin(__builtin_amdgcn_exp2f)
#define EXP2F(x) __builtin_amdgcn_exp2f(x)
#else
#define EXP2F(x) exp2f(x)
#endif

// async global -> LDS, 16 bytes per lane (dest must be base + lane*16)
__device__ __forceinline__ void gload16(const void* g, void* l) {
    __builtin_amdgcn_global_load_lds((__attribute__((address_space(1))) unsigned int*)g,
                                     (__attribute__((address_space(3))) unsigned int*)l,
                                     16, 0, 0);
}

__device__ __forceinline__ void barrier_lgkm() {
    asm volatile("s_waitcnt lgkmcnt(0)" ::: "memory");
    __builtin_amdgcn_s_barrier();
}

// ---------------- fused fp32 -> bf16 convert (5 segments, vectorized) ----------------
struct CvtArgs {
    const float* in[5];
    unsigned short* out[5];
    int n4[5];   // element count / 4
};
typedef __attribute__((ext_vector_type(4))) float float4v;
typedef __attribute__((ext_vector_type(4))) unsigned short ushort4v;
__global__ __launch_bounds__(256) void cvt5_kernel(CvtArgs a) {
    int base = blockIdx.x * 256 + threadIdx.x;
    int stride = gridDim.x * 256;
#pragma unroll
    for (int s = 0; s < 5; ++s) {
        const float4v* ip = (const float4v*)a.in[s];
        ushort4v* op = (ushort4v*)a.out[s];
        for (int i = base; i < a.n4[s]; i += stride) {
            float4v v = ip[i];
            ushort4v o;
            o[0] = f2bf(v[0]); o[1] = f2bf(v[1]); o[2] = f2bf(v[2]); o[3] = f2bf(v[3]);
            op[i] = o;
        }
    }
}

// ---------------- mask -> bit pack (16 keys per ushort) ----------------
__global__ __launch_bounds__(256) void maskbits_kernel(const float* __restrict__ mask,
                                                       unsigned short* __restrict__ mb, int n) {
    int i = blockIdx.x * 256 + threadIdx.x;
    if (i >= n) return;
    const float4v* mp = (const float4v*)(mask + (size_t)i * 16);
    unsigned int bits = 0;
#pragma unroll
    for (int q = 0; q < 4; ++q) {
        float4v v = mp[q];
#pragma unroll
        for (int j = 0; j < 4; ++j) bits |= (v[j] > 0.5f) ? (1u << (q * 4 + j)) : 0u;
    }
    mb[i] = (unsigned short)bits;
}

// ---------------- LayerNorm (fp32 in, bf16 out) ----------------
__global__ __launch_bounds__(256) void ln_kernel(const float* __restrict__ x,
                                                 const float* __restrict__ g,
                                                 const float* __restrict__ b,
                                                 unsigned short* __restrict__ out) {
    int t = blockIdx.x;
    int tid = threadIdx.x;
    const float* xr = x + (size_t)t * CC;
    float v0 = xr[tid], v1 = xr[tid + 256], v2 = xr[tid + 512];
    float s = v0 + v1 + v2;
    float s2 = v0 * v0 + v1 * v1 + v2 * v2;
#pragma unroll
    for (int off = 1; off < 64; off <<= 1) {
        s  += __shfl_xor(s, off);
        s2 += __shfl_xor(s2, off);
    }
    __shared__ float red[8];
    int wv = tid >> 6, lane = tid & 63;
    if (lane == 0) { red[wv] = s; red[wv + 4] = s2; }
    __syncthreads();
    s  = red[0] + red[1] + red[2] + red[3];
    s2 = red[4] + red[5] + red[6] + red[7];
    float mu   = s * (1.0f / CC);
    float var  = s2 * (1.0f / CC) - mu * mu;
    float rstd = rsqrtf(var + 1e-5f);
    unsigned short* orow = out + (size_t)t * CC;
    orow[tid]       = f2bf((v0 - mu) * rstd * g[tid]       + b[tid]);
    orow[tid + 256] = f2bf((v1 - mu) * rstd * g[tid + 256] + b[tid + 256]);
    orow[tid + 512] = f2bf((v2 - mu) * rstd * g[tid + 512] + b[tid + 512]);
}

// ---------------- GEMM (m97 structure): C[M,N] = A[M,K] @ Bw[N,K]^T ----------------
// EPI 0: store bf16 (no bias)            -> qkv
// EPI 1: +bias +res(f32), store f32      -> proj + residual
// EPI 2: +bias, exact GELU, store bf16   -> fc1
// EPI 3: +bias +res(f32), store f32      -> fc2 + residual (d_out)
// BM: 128 (wave 64x64) or 64 (wave 32x64); BN fixed 128.
template <int EPI, int BM>
__global__ __launch_bounds__(256) void gemm_bt(const unsigned short* __restrict__ A,
                                               const unsigned short* __restrict__ Bw,
                                               const float* __restrict__ bias,
                                               const float* __restrict__ res,
                                               void* __restrict__ out,
                                               int M, int N, int K) {
    constexpr int MI = BM / 32;           // acc rows of 16: 4 or 2
    __shared__ alignas(16) unsigned short As[BM * 32];
    __shared__ alignas(16) unsigned short Bs[128 * 32];
    int tid = threadIdx.x;
    int lane = tid & 63, wv = tid >> 6;
    int l16 = lane & 15, lg = lane >> 4;
    int bm = blockIdx.x, bn = blockIdx.y;
    int wm = (wv & 1) * (BM / 2), wn = (wv >> 1) * 64;

    f32x4 acc[MI][4];
#pragma unroll
    for (int i = 0; i < MI; ++i)
#pragma unroll
        for (int j = 0; j < 4; ++j) acc[i][j] = f32x4{0.f, 0.f, 0.f, 0.f};

    const unsigned short* Ab = A + (size_t)bm * BM * K;
    const unsigned short* Bb = Bw + (size_t)bn * 128 * K;

    for (int k0 = 0; k0 < K; k0 += 32) {
        __syncthreads();
        constexpr int NCA = (BM * 4) / 256;   // A chunks per thread
#pragma unroll
        for (int i = 0; i < NCA; ++i) {
            int c = tid + i * 256;
            int row = c >> 2, cc = (c & 3) * 8;
            gload16(Ab + (size_t)row * K + k0 + cc, &As[c * 8]);
        }
#pragma unroll
        for (int i = 0; i < 2; ++i) {
            int c = tid + i * 256;
            int row = c >> 2, cc = (c & 3) * 8;
            gload16(Bb + (size_t)row * K + k0 + cc, &Bs[c * 8]);
        }
        __syncthreads();
        bf16x8 af[MI], bfr[4];
#pragma unroll
        for (int mi = 0; mi < MI; ++mi) af[mi]  = *(const bf16x8*)&As[(wm + mi * 16 + l16) * 32 + lg * 8];
#pragma unroll
        for (int ni = 0; ni < 4; ++ni) bfr[ni] = *(const bf16x8*)&Bs[(wn + ni * 16 + l16) * 32 + lg * 8];
#pragma unroll
        for (int mi = 0; mi < MI; ++mi)
#pragma unroll
            for (int ni = 0; ni < 4; ++ni)
                acc[mi][ni] = __builtin_amdgcn_mfma_f32_16x16x32_bf16(af[mi], bfr[ni], acc[mi][ni], 0, 0, 0);
    }

#pragma unroll
    for (int ni = 0; ni < 4; ++ni) {
        int col = bn * 128 + wn + ni * 16 + l16;
        float bv = (EPI == 0) ? 0.f : bias[col];
#pragma unroll
        for (int mi = 0; mi < MI; ++mi) {
#pragma unroll
            for (int r = 0; r < 4; ++r) {
                int row = bm * BM + wm + mi * 16 + lg * 4 + r;
                float v = acc[mi][ni][r];
                size_t idx = (size_t)row * N + col;
                if (EPI == 0) {
                    ((unsigned short*)out)[idx] = f2bf(v);
                } else if (EPI == 1) {
                    ((float*)out)[idx] = v + bv + res[idx];
                } else if (EPI == 2) {
                    v += bv;
                    v = 0.5f * v * (1.0f + erff(v * 0.70710678118f));
                    ((unsigned short*)out)[idx] = f2bf(v);
                } else {
                    ((float*)out)[idx] = v + bv + res[idx];
                }
            }
        }
    }
}

// ---------------- Flash attention v3 ----------------
// KVB=64 double-buffered; K XOR-swizzled (conflict-free b128); V^T pitch-68 packed
// (conflict-free b32 writes + b64 reads); exp2-domain softmax with defer-max;
// global->reg prefetch overlapped via raw s_barrier (no vmcnt drain).
#define KVB 64
#define ANT (NN/KVB)   // 32 tiles
#define VP 68          // Vt pitch (ushorts), 136B rows: b64-aligned, conflict-free
__global__ __launch_bounds__(256) void attn_kernel(const unsigned short* __restrict__ qkv,
                                                   const unsigned short* __restrict__ maskb,
                                                   unsigned short* __restrict__ o) {
    __shared__ alignas(16) unsigned short Ks[2][64 * 64];
    __shared__ alignas(16) unsigned short Vt[2][64 * VP];
    int tid = threadIdx.x;
    int lane = tid & 63, wv = tid >> 6;
    int l16 = lane & 15, lg = lane >> 4;
    int qb = blockIdx.x;
    int bh = blockIdx.y;
    int b = bh / HH, h = bh % HH;
    int qrow = qb * 64 + wv * 16 + l16;

    // Q: load, fold 0.125*log2(e) (exp2-domain softmax)
    const unsigned short* qp = qkv + ((size_t)(b * NN + qrow)) * 2304 + h * DD;
    bf16x8 q0r = *(const bf16x8*)(qp + 8 * lg);
    bf16x8 q1r = *(const bf16x8*)(qp + 32 + 8 * lg);
    const float QSC = 0.125f * 1.4426950408889634f;
    bf16x8 q0, q1;
#pragma unroll
    for (int j = 0; j < 8; ++j) {
        q0[j] = (short)f2bf(bf2f((unsigned short)q0r[j]) * QSC);
        q1[j] = (short)f2bf(bf2f((unsigned short)q1r[j]) * QSC);
    }

    const unsigned short* mrow  = maskb + ((size_t)(b * NN + qrow)) * 128;
    const unsigned short* kbase = qkv + (size_t)b * NN * 2304 + 768 + h * DD;
    const unsigned short* vbase = qkv + (size_t)b * NN * 2304 + 1536 + h * DD;

    // staging maps
    int kc1_row = tid >> 3, kc7 = tid & 7;            // K rows 0..31
    int kc2_row = kc1_row + 32;                        // K rows 32..63
    int klds1 = kc1_row * 64 + ((kc7 ^ (kc1_row & 7)) * 8);
    int klds2 = kc2_row * 64 + ((kc7 ^ (kc2_row & 7)) * 8);
    int kp = tid & 31, dg = tid >> 5;                  // V: key-pair 2kp/2kp+1, d-group dg*8

    // hot-loop LDS read bases
    int sw = l16 & 7;
    int kb0 = l16 * 64 + ((lg ^ sw) * 8);              // + ks*1024
    int kb1 = l16 * 64 + (((lg + 4) ^ sw) * 8);
    int vbo = l16 * VP + lg * 4;                       // + db*16*VP + ks*16

    bf16x8 ka, kb, va, vb;
    unsigned long long mb_cur, mb_nxt;

    f32x4 oa[4];
#pragma unroll
    for (int i = 0; i < 4; ++i) oa[i] = f32x4{0.f, 0.f, 0.f, 0.f};
    float mrun = -INFINITY, lrun = 0.f;

    auto LOAD = [&](int t) {
        ka = *(const bf16x8*)(kbase + (size_t)(t * KVB + kc1_row) * 2304 + kc7 * 8);
        kb = *(const bf16x8*)(kbase + (size_t)(t * KVB + kc2_row) * 2304 + kc7 * 8);
        va = *(const bf16x8*)(vbase + (size_t)(t * KVB + 2 * kp) * 2304 + dg * 8);
        vb = *(const bf16x8*)(vbase + (size_t)(t * KVB + 2 * kp + 1) * 2304 + dg * 8);
        mb_nxt = *(const unsigned long long*)(mrow + t * 4);
    };
    auto WRITE = [&](int s) {
        unsigned short* Kd = Ks[s];
        *(bf16x8*)&Kd[klds1] = ka;
        *(bf16x8*)&Kd[klds2] = kb;
        unsigned int* VtU = (unsigned int*)Vt[s];
#pragma unroll
        for (int j = 0; j < 8; ++j)
            VtU[(dg * 8 + j) * (VP / 2) + kp] =
                (unsigned int)(unsigned short)va[j] | ((unsigned int)(unsigned short)vb[j] << 16);
    };

    LOAD(0);
    WRITE(0);
    mb_cur = mb_nxt;
    int cur = 0;

    for (int kt = 0; kt < ANT; ++kt) {
        bool pre = (kt + 1 < ANT);
        if (pre) LOAD(kt + 1);
        barrier_lgkm();                      // buf[cur] writes visible; no vmcnt drain
        const unsigned short* Ksc = Ks[cur];
        const unsigned short* Vtc = Vt[cur];

        // ---- QK^T (S^T layout: key=lg*4+r within ks-group, qrow=l16) ----
        float sv[16];
#pragma unroll
        for (int ks = 0; ks < 4; ++ks) {
            bf16x8 k0 = *(const bf16x8*)&Ksc[kb0 + ks * 1024];
            bf16x8 k1 = *(const bf16x8*)&Ksc[kb1 + ks * 1024];
            f32x4 sa = f32x4{0.f, 0.f, 0.f, 0.f};
            sa = __builtin_amdgcn_mfma_f32_16x16x32_bf16(k0, q0, sa, 0, 0, 0);
            sa = __builtin_amdgcn_mfma_f32_16x16x32_bf16(k1, q1, sa, 0, 0, 0);
            unsigned int m16 = (unsigned int)(mb_cur >> (ks * 16 + lg * 4));
#pragma unroll
            for (int r = 0; r < 4; ++r) {
                float mbit = (float)((m16 >> r) & 1u);
                sv[ks * 4 + r] = fmaf(mbit, -144269.5f, sa[r]);
            }
        }
        float tmax = sv[0];
#pragma unroll
        for (int i = 1; i < 16; ++i) tmax = fmaxf(tmax, sv[i]);
        tmax = fmaxf(tmax, __shfl_xor(tmax, 16));
        tmax = fmaxf(tmax, __shfl_xor(tmax, 32));

        // ---- defer-max rescale (exp2 domain, THR=11.5 bits) ----
        if (__any(tmax > mrun + 11.5f)) {
            float mnew = fmaxf(mrun, tmax);
            float sc = EXP2F(mrun - mnew);
            lrun *= sc;
#pragma unroll
            for (int db = 0; db < 4; ++db) {
                oa[db][0] *= sc; oa[db][1] *= sc; oa[db][2] *= sc; oa[db][3] *= sc;
            }
            mrun = mnew;
        }

        // ---- P = exp2(S - m), bf16 fragments ----
        float ps = 0.f;
        bf16x4 pf[4];
#pragma unroll
        for (int ks = 0; ks < 4; ++ks)
#pragma unroll
            for (int r = 0; r < 4; ++r) {
                float p = EXP2F(sv[ks * 4 + r] - mrun);
                ps += p;
                pf[ks][r] = (short)f2bf(p);
            }
        lrun += ps;

        // ---- PV: O^T[d][qrow] += V^T[d][key] * P^T[key][qrow] ----
#pragma unroll
        for (int ks = 0; ks < 4; ++ks)
#pragma unroll
            for (int db = 0; db < 4; ++db) {
                bf16x4 vf = *(const bf16x4*)&Vtc[vbo + db * 16 * VP + ks * 16];
                oa[db] = __builtin_amdgcn_mfma_f32_16x16x16bf16_1k(vf, pf[ks], oa[db], 0, 0, 0);
            }

        barrier_lgkm();                      // all reads of buf[cur] done
        if (pre) { WRITE(cur ^ 1); cur ^= 1; mb_cur = mb_nxt; }
    }

    float lt = lrun;
    lt += __shfl_xor(lt, 16);
    lt += __shfl_xor(lt, 32);
    float inv = 1.0f / lt;
    unsigned short* op = o + ((size_t)(b * NN + qrow)) * CC + h * DD;
#pragma unroll
    for (int db = 0; db < 4; ++db) {
        bf16x4 ov;
#pragma unroll
        for (int r = 0; r < 4; ++r) ov[r] = (short)f2bf(oa[db][r] * inv);
        *(bf16x4*)&op[db * 16 + lg * 4] = ov;
    }
}

// ---------------- host launch ----------------
extern "C" void kernel_launch(void* const* d_in, const int* in_sizes, int n_in,
                              void* d_out, int out_size, void* d_ws, size_t ws_size,
                              hipStream_t stream) {
    const float* x    = (const float*)d_in[0];
    const float* mask = (const float*)d_in[1];
    const float* g1   = (const float*)d_in[2];
    const float* b1   = (const float*)d_in[3];
    const float* Wq   = (const float*)d_in[4];
    const float* Wkv  = (const float*)d_in[5];
    const float* Wp   = (const float*)d_in[6];
    const float* bp   = (const float*)d_in[7];
    const float* g2   = (const float*)d_in[8];
    const float* b2   = (const float*)d_in[9];
    const float* W1   = (const float*)d_in[10];
    const float* bf1  = (const float*)d_in[11];
    const float* W2   = (const float*)d_in[12];
    const float* bf2  = (const float*)d_in[13];
    float* out = (float*)d_out;

    char* w = (char*)d_ws;
    unsigned short* wqkv = (unsigned short*)w;      w += (size_t)2304 * 768 * 2;
    unsigned short* wp   = (unsigned short*)w;      w += (size_t)768 * 768 * 2;
    unsigned short* w1   = (unsigned short*)w;      w += (size_t)3072 * 768 * 2;
    unsigned short* w2   = (unsigned short*)w;      w += (size_t)768 * 3072 * 2;
    unsigned short* xn   = (unsigned short*)w;      w += (size_t)TT * CC * 2;
    unsigned short* qkv  = (unsigned short*)w;      w += (size_t)TT * 2304 * 2;
    unsigned short* mb   = (unsigned short*)w;      w += (size_t)BB * NN * 128 * 2;
    unsigned short* obuf = (unsigned short*)w;      w += (size_t)TT * CC * 2;
    float*          x1   = (float*)w;               w += (size_t)TT * CC * 4;
    unsigned short* xn2  = (unsigned short*)w;      w += (size_t)TT * CC * 2;
    unsigned short* hbuf = (unsigned short*)w;      w += (size_t)TT * HID * 2;

    CvtArgs ca;
    ca.in[0] = Wq;  ca.out[0] = wqkv;             ca.n4[0] = 768 * 768 / 4;
    ca.in[1] = Wkv; ca.out[1] = wqkv + 768 * 768; ca.n4[1] = 1536 * 768 / 4;
    ca.in[2] = Wp;  ca.out[2] = wp;               ca.n4[2] = 768 * 768 / 4;
    ca.in[3] = W1;  ca.out[3] = w1;               ca.n4[3] = 3072 * 768 / 4;
    ca.in[4] = W2;  ca.out[4] = w2;               ca.n4[4] = 768 * 3072 / 4;
    cvt5_kernel<<<1024, 256, 0, stream>>>(ca);

    {
        int n = BB * NN * (NN / 16);
        maskbits_kernel<<<(n + 255) / 256, 256, 0, stream>>>(mask, mb, n);
    }

    ln_kernel<<<TT, 256, 0, stream>>>(x, g1, b1, xn);

    gemm_bt<0, 128><<<dim3(TT / 128, 2304 / 128), 256, 0, stream>>>(xn, wqkv, nullptr, nullptr, qkv, TT, 2304, 768);

    attn_kernel<<<dim3(NN / 64, BB * HH), 256, 0, stream>>>(qkv, mb, obuf);

    gemm_bt<1, 64><<<dim3(TT / 64, 768 / 128), 256, 0, stream>>>(obuf, wp, bp, x, x1, TT, 768, 768);

    ln_kernel<<<TT, 256, 0, stream>>>(x1, g2, b2, xn2);

    gemm_bt<2, 128><<<dim3(TT / 128, HID / 128), 256, 0, stream>>>(xn2, w1, bf1, nullptr, hbuf, TT, HID, 768);

    gemm_bt<3, 64><<<dim3(TT / 64, 768 / 128), 256, 0, stream>>>(hbuf, w2, bf2, x1, out, TT, 768, HID);
}